// Round 11
// baseline (206.677 us; speedup 1.0000x reference)
//
#include <hip/hip_runtime.h>

#define LOG2E 1.44269504088896340736f

// ds_swizzle BitMode: src_lane = ((lane & and) | or) ^ xor; imm=(xor<<10)|(or<<5)|and
// Masks 0x01C/0x03C/0x05C proven in R2/R9/R10 (keep bits[4:2], select unit j).
#define SWZ(v, imm) __int_as_float(__builtin_amdgcn_ds_swizzle(__float_as_int(v), (imm)))

typedef __attribute__((address_space(3))) char lds_char_t;
typedef __attribute__((address_space(1))) const char g_char_t;

#define WAITVM(n) asm volatile("s_waitcnt vmcnt(" #n ")" ::: "memory")

// R10 structure (unit-owner + LDS staging + counted vmcnt) with 4x TLP:
// 16 lanes per row = FOUR independent copies of the 4-lane unit-owner group
// (bits[1:0]=unit k, bits[3:2]=copy, bit[4]+=row-in-wave). Each copy
// redundantly computes its row -> no cross-copy traffic; h-broadcast swizzles
// (and=0x1C) stay within each copy's quad. 4 rows/wave -> 2048 waves = 2/SIMD:
// every SIMD holds 2 waves, so chain stalls of one are filled by the other.
// Staging: per-wave private 4KB LDS (2 bufs x 8 steps x 4 rows x 64B),
// 2 global_load_lds issues per 8-step block, WAITVM(2) double-buffer
// discipline. Waves fully independent -> no barriers.
__global__ __launch_bounds__(256, 1)
void lstm_tlp4_kernel(const float* __restrict__ X,    // [8192,512,16]
                      const float* __restrict__ Wg,   // [16,12]
                      const float* __restrict__ Ug,   // [3,12]
                      const float* __restrict__ bg,   // [12]
                      const float* __restrict__ Wd,   // [3]
                      const float* __restrict__ bd,   // [1]
                      float* __restrict__ out)        // [8192]
{
    constexpr int T = 512;
    __shared__ __align__(16) char lds[16384];  // 4 waves x (2 bufs x 2048B)

    const int tid  = threadIdx.x;      // 0..255
    const int lane = tid & 63;
    const int w    = tid >> 6;         // wave id 0..3
    const int rw   = (lane >> 4) & 3;  // row within wave 0..3
    const int k    = lane & 3;         // unit (3 dups 2)
    const int kk   = (k == 3) ? 2 : k;
    const int lr   = tid & 15;         // lane within row group (copy*4 + k)
    const int b    = blockIdx.x * 16 + (tid >> 4);   // this lane's batch row

    const int ci = kk, cf = 3 + kk, cg = 6 + kk, co = 9 + kk;

    // weights with quarter-rotation by row-in-wave (bank-conflict-free reads):
    // chunk J holds features 4*((J+rw)&3)+e
    float wi[16], wf[16], wgt[16], wo[16];
#pragma unroll
    for (int J = 0; J < 4; ++J) {
        const int fbase = ((J + rw) & 3) * 4;
#pragma unroll
        for (int e = 0; e < 4; ++e) {
            const float* row = Wg + (size_t)(fbase + e) * 12;
            wi [J*4+e] = row[ci];
            wf [J*4+e] = row[cf];
            wgt[J*4+e] = row[cg];
            wo [J*4+e] = row[co];
        }
    }
    const float ui0 = Ug[ci], ui1 = Ug[12+ci], ui2 = Ug[24+ci];
    const float uf0 = Ug[cf], uf1 = Ug[12+cf], uf2 = Ug[24+cf];
    const float ug0 = Ug[cg], ug1 = Ug[12+cg], ug2 = Ug[24+cg];
    const float uo0 = Ug[co], uo1 = Ug[12+co], uo2 = Ug[24+co];
    const float bias_i = bg[ci], bias_f = bg[cf], bias_g = bg[cg], bias_o = bg[co];
    const float wd0 = Wd[0], wd1 = Wd[1], wd2 = Wd[2], bdv = bd[0];

    const int rot0 = (0 + rw) & 3, rot1 = (1 + rw) & 3,
              rot2 = (2 + rw) & 3, rot3 = (3 + rw) & 3;

    float c = 0.f, h0 = 0.f, h1 = 0.f, h2 = 0.f;

    // ---- staging source mapping (per lane, for the wave's 4 rows) ----
    // issue i covers rows {i*2, i*2+1}: lane l -> row2=(l>>5), step=(l>>2)&7,
    // q=l&3; LDS dest auto = base + i*1024 + l*16  == row*512 + step*64 + q*16.
    const int rowbase = blockIdx.x * 16 + w * 4;
    const int srow    = rowbase + (lane >> 5);
    const float4* X4  = reinterpret_cast<const float4*>(X);
    const float4* g0  = X4 + (size_t)srow * (T * 4) + ((lane >> 2) & 7) * 4 + (lane & 3);
    const float4* g1  = g0 + (size_t)2 * (T * 4);
    const int woff    = w * 4096;              // this wave's LDS region

#define STAGE_BLK(tblk, bufsel) do {                                          \
    lds_char_t* lp0_ = (lds_char_t*)(uintptr_t)(lds + woff + (bufsel));       \
    lds_char_t* lp1_ = (lds_char_t*)(uintptr_t)(lds + woff + (bufsel) + 1024);\
    __builtin_amdgcn_global_load_lds((g_char_t*)(const void*)(g0 + (size_t)(tblk) * 32), \
                                     lp0_, 16, 0, 0);                         \
    __builtin_amdgcn_global_load_lds((g_char_t*)(const void*)(g1 + (size_t)(tblk) * 32), \
                                     lp1_, 16, 0, 0);                         \
} while (0)

#define LOAD_XQ(D0, D1, D2, D3, bufsel, s) do {                               \
    const float4* lp_ = (const float4*)(lds + woff + (bufsel) + rw * 512 + (s) * 64); \
    D0 = lp_[rot0]; D1 = lp_[rot1]; D2 = lp_[rot2]; D3 = lp_[rot3];           \
} while (0)

#define STEP(X0, X1, X2, X3) do {                                             \
    const float xs[16] = {X0.x,X0.y,X0.z,X0.w, X1.x,X1.y,X1.z,X1.w,           \
                          X2.x,X2.y,X2.z,X2.w, X3.x,X3.y,X3.z,X3.w};          \
    float zi = bias_i, zf = bias_f, zg = bias_g, zo = bias_o;                 \
    _Pragma("unroll")                                                         \
    for (int f_ = 0; f_ < 16; ++f_) {                                         \
        zi = fmaf(xs[f_], wi[f_],  zi);                                       \
        zf = fmaf(xs[f_], wf[f_],  zf);                                       \
        zg = fmaf(xs[f_], wgt[f_], zg);                                       \
        zo = fmaf(xs[f_], wo[f_],  zo);                                       \
    }                                                                         \
    zi = fmaf(h0, ui0, zi); zi = fmaf(h1, ui1, zi); zi = fmaf(h2, ui2, zi);   \
    zf = fmaf(h0, uf0, zf); zf = fmaf(h1, uf1, zf); zf = fmaf(h2, uf2, zf);   \
    zg = fmaf(h0, ug0, zg); zg = fmaf(h1, ug1, zg); zg = fmaf(h2, ug2, zg);   \
    zo = fmaf(h0, uo0, zo); zo = fmaf(h1, uo1, zo); zo = fmaf(h2, uo2, zo);   \
    const float ei = __builtin_amdgcn_exp2f(zi * (-LOG2E));                   \
    const float ef = __builtin_amdgcn_exp2f(zf * (-LOG2E));                   \
    const float eg = __builtin_amdgcn_exp2f(zg * (-2.0f * LOG2E));            \
    const float eo = __builtin_amdgcn_exp2f(zo * (-LOG2E));                   \
    const float ai = __builtin_amdgcn_rcpf(1.0f + ei);                        \
    const float af = __builtin_amdgcn_rcpf(1.0f + ef);                        \
    const float ag = fmaf(2.0f, __builtin_amdgcn_rcpf(1.0f + eg), -1.0f);     \
    const float ao = __builtin_amdgcn_rcpf(1.0f + eo);                        \
    c = fmaf(af, c, ai * ag);                                                 \
    const float ec = __builtin_amdgcn_exp2f(c * (-2.0f * LOG2E));             \
    const float th = fmaf(2.0f, __builtin_amdgcn_rcpf(1.0f + ec), -1.0f);     \
    const float hk = ao * th;                                                 \
    h0 = SWZ(hk, 0x01C); h1 = SWZ(hk, 0x03C); h2 = SWZ(hk, 0x05C);            \
} while (0)

    // prologue: two 8-step blocks in flight (2 issues each), wait for first
    STAGE_BLK(0, 0);
    STAGE_BLK(1, 2048);
    WAITVM(2);
    __builtin_amdgcn_sched_barrier(0);

    float4 xa0, xa1, xa2, xa3, xb0, xb1, xb2, xb3;
    LOAD_XQ(xa0, xa1, xa2, xa3, 0, 0);

    for (int blk = 0; blk < 64; ++blk) {
        const int bufsel = (blk & 1) ? 2048 : 0;
#pragma unroll
        for (int s = 0; s < 8; ++s) {
            if ((s & 1) == 0) {
                if (s < 7) LOAD_XQ(xb0, xb1, xb2, xb3, bufsel, s + 1);
                STEP(xa0, xa1, xa2, xa3);
            } else {
                if (s < 7) LOAD_XQ(xa0, xa1, xa2, xa3, bufsel, s + 1);
                STEP(xb0, xb1, xb2, xb3);
            }
        }
        // buf[bufsel] fully consumed; refill it with block blk+2
        __builtin_amdgcn_sched_barrier(0);
        if (blk + 2 < 64) {
            STAGE_BLK(blk + 2, bufsel);
            WAITVM(2);   // waits for block blk+1 (issued a full block ago)
        } else {
            WAITVM(0);
        }
        __builtin_amdgcn_sched_barrier(0);
        if (blk < 63) {
            LOAD_XQ(xa0, xa1, xa2, xa3, bufsel ^ 2048, 0);
        }
    }

    if (lr == 0) {   // copy 0, unit 0 writes the head
        float acc = bdv;
        acc = fmaf(h0, wd0, acc);
        acc = fmaf(h1, wd1, acc);
        acc = fmaf(h2, wd2, acc);
        const float e = __builtin_amdgcn_exp2f(-LOG2E * acc);
        out[b] = __builtin_amdgcn_rcpf(1.0f + e);
    }
#undef STAGE_BLK
#undef LOAD_XQ
#undef STEP
}

extern "C" void kernel_launch(void* const* d_in, const int* in_sizes, int n_in,
                              void* d_out, int out_size, void* d_ws, size_t ws_size,
                              hipStream_t stream) {
    const float* X  = (const float*)d_in[0];
    const float* W  = (const float*)d_in[1];
    const float* U  = (const float*)d_in[2];
    const float* bg = (const float*)d_in[3];
    const float* Wd = (const float*)d_in[4];
    const float* bd = (const float*)d_in[5];
    float* out = (float*)d_out;

    dim3 grid(8192 / 16);   // 512 blocks x 256 threads = 2048 waves (2/SIMD)
    dim3 block(256);
    hipLaunchKernelGGL(lstm_tlp4_kernel, grid, block, 0, stream,
                       X, W, U, bg, Wd, bd, out);
}

// Round 12
// 150.972 us; speedup vs baseline: 1.3690x; 1.3690x over previous
//
#include <hip/hip_runtime.h>

#define LOG2E 1.44269504088896340736f

// ds_swizzle BitMode: src_lane = ((lane & and) | or) ^ xor; imm=(xor<<10)|(or<<5)|and
// Gather masks (src<<5)|0x10 proven in R7; staging machinery proven in R11.
#define SWZ(v, imm) __int_as_float(__builtin_amdgcn_ds_swizzle(__float_as_int(v), (imm)))

typedef __attribute__((address_space(3))) char lds_char_t;
typedef __attribute__((address_space(1))) const char g_char_t;

#define WAITVM(n) asm volatile("s_waitcnt vmcnt(" #n ")" ::: "memory")

// 16 lanes/row, NON-redundant: lane lr = q*4+k activates gate q of unit k
// (k==3 dups unit 2). ONE ds_swizzle round/step (12 gathers, and=0x10 keeps
// row bit4; bit5 per-half implicit); c0..c2/h0..h2 kept fully local per lane.
// X staged through LDS (R11 machinery): per-wave 4KB region, 8-step blocks,
// double-buffered, 2 global_load_lds issues per block, counted WAITVM(2).
// 512 blocks x 256 thr = 2048 waves = 2/SIMD (proven issue-saturating in R11).
__global__ __launch_bounds__(256, 1)
void lstm_or_staged_kernel(const float* __restrict__ X,    // [8192,512,16]
                           const float* __restrict__ Wg,   // [16,12]
                           const float* __restrict__ Ug,   // [3,12]
                           const float* __restrict__ bg,   // [12]
                           const float* __restrict__ Wd,   // [3]
                           const float* __restrict__ bd,   // [1]
                           float* __restrict__ out)        // [8192]
{
    constexpr int T = 512;
    __shared__ __align__(16) char lds[16384];  // 4 waves x (2 bufs x 2048B)

    const int tid  = threadIdx.x;      // 0..255
    const int lane = tid & 63;
    const int w    = tid >> 6;         // wave id 0..3
    const int rw   = (lane >> 4) & 3;  // row within wave 0..3
    const int lr   = tid & 15;         // lane within row group
    const int q    = (lr >> 2) & 3;    // gate: 0=i,1=f,2=g,3=o (Keras order)
    const int k    = lr & 3;           // unit (3 dups 2)
    const int kk   = (k == 3) ? 2 : k;
    const int col  = q * 3 + kk;
    const int b    = blockIdx.x * 16 + (tid >> 4);

    // this lane's weight column, in rotated chunk order:
    // chunk J holds features 4*((J+rw)&3)+e  (matches LOAD_XQ rotation)
    float wv[16];
#pragma unroll
    for (int J = 0; J < 4; ++J) {
        const int fbase = ((J + rw) & 3) * 4;
#pragma unroll
        for (int e = 0; e < 4; ++e)
            wv[J * 4 + e] = Wg[(size_t)(fbase + e) * 12 + col];
    }
    const float u0 = Ug[col], u1 = Ug[12 + col], u2 = Ug[24 + col];
    const float bias = bg[col];
    const float wd0 = Wd[0], wd1 = Wd[1], wd2 = Wd[2], bdv = bd[0];

    // act(z) = pa * rcp(1 + exp2(z*pre)) + pb ; tanh for q==2 (g)
    const bool is_g = (q == 2);
    const float pre = is_g ? (-2.0f * LOG2E) : (-LOG2E);
    const float pa  = is_g ? 2.0f : 1.0f;
    const float pb  = is_g ? -1.0f : 0.0f;

    float c0 = 0.f, c1 = 0.f, c2 = 0.f;
    float h0 = 0.f, h1 = 0.f, h2 = 0.f;

    // ---- staging source mapping (R11-proven) ----
    const int rowbase = blockIdx.x * 16 + w * 4;
    const int srow    = rowbase + (lane >> 5);
    const float4* X4  = reinterpret_cast<const float4*>(X);
    const float4* g0  = X4 + (size_t)srow * (T * 4) + ((lane >> 2) & 7) * 4 + (lane & 3);
    const float4* g1  = g0 + (size_t)2 * (T * 4);
    const int woff    = w * 4096;

    const int rot0 = (0 + rw) & 3, rot1 = (1 + rw) & 3,
              rot2 = (2 + rw) & 3, rot3 = (3 + rw) & 3;

#define STAGE_BLK(tblk, bufsel) do {                                          \
    lds_char_t* lp0_ = (lds_char_t*)(uintptr_t)(lds + woff + (bufsel));       \
    lds_char_t* lp1_ = (lds_char_t*)(uintptr_t)(lds + woff + (bufsel) + 1024);\
    __builtin_amdgcn_global_load_lds((g_char_t*)(const void*)(g0 + (size_t)(tblk) * 32), \
                                     lp0_, 16, 0, 0);                         \
    __builtin_amdgcn_global_load_lds((g_char_t*)(const void*)(g1 + (size_t)(tblk) * 32), \
                                     lp1_, 16, 0, 0);                         \
} while (0)

#define LOAD_XQ(D0, D1, D2, D3, bufsel, s) do {                               \
    const float4* lp_ = (const float4*)(lds + woff + (bufsel) + rw * 512 + (s) * 64); \
    D0 = lp_[rot0]; D1 = lp_[rot1]; D2 = lp_[rot2]; D3 = lp_[rot3];           \
} while (0)

#define STEP(X0, X1, X2, X3) do {                                             \
    float z = bias;                                                           \
    z = fmaf(X0.x, wv[0],  z); z = fmaf(X0.y, wv[1],  z);                     \
    z = fmaf(X0.z, wv[2],  z); z = fmaf(X0.w, wv[3],  z);                     \
    z = fmaf(X1.x, wv[4],  z); z = fmaf(X1.y, wv[5],  z);                     \
    z = fmaf(X1.z, wv[6],  z); z = fmaf(X1.w, wv[7],  z);                     \
    z = fmaf(X2.x, wv[8],  z); z = fmaf(X2.y, wv[9],  z);                     \
    z = fmaf(X2.z, wv[10], z); z = fmaf(X2.w, wv[11], z);                     \
    z = fmaf(X3.x, wv[12], z); z = fmaf(X3.y, wv[13], z);                     \
    z = fmaf(X3.z, wv[14], z); z = fmaf(X3.w, wv[15], z);                     \
    z = fmaf(h0, u0, z); z = fmaf(h1, u1, z); z = fmaf(h2, u2, z);            \
    const float e_  = __builtin_amdgcn_exp2f(z * pre);                        \
    const float val = fmaf(pa, __builtin_amdgcn_rcpf(1.0f + e_), pb);         \
    const float iv0 = SWZ(val, (0  << 5) | 0x10);                             \
    const float iv1 = SWZ(val, (1  << 5) | 0x10);                             \
    const float iv2 = SWZ(val, (2  << 5) | 0x10);                             \
    const float fv0 = SWZ(val, (4  << 5) | 0x10);                             \
    const float fv1 = SWZ(val, (5  << 5) | 0x10);                             \
    const float fv2 = SWZ(val, (6  << 5) | 0x10);                             \
    const float gv0 = SWZ(val, (8  << 5) | 0x10);                             \
    const float gv1 = SWZ(val, (9  << 5) | 0x10);                             \
    const float gv2 = SWZ(val, (10 << 5) | 0x10);                             \
    const float ov0 = SWZ(val, (12 << 5) | 0x10);                             \
    const float ov1 = SWZ(val, (13 << 5) | 0x10);                             \
    const float ov2 = SWZ(val, (14 << 5) | 0x10);                             \
    c0 = fmaf(fv0, c0, iv0 * gv0);                                            \
    c1 = fmaf(fv1, c1, iv1 * gv1);                                            \
    c2 = fmaf(fv2, c2, iv2 * gv2);                                            \
    const float ec0 = __builtin_amdgcn_exp2f(c0 * (-2.0f * LOG2E));           \
    const float ec1 = __builtin_amdgcn_exp2f(c1 * (-2.0f * LOG2E));           \
    const float ec2 = __builtin_amdgcn_exp2f(c2 * (-2.0f * LOG2E));           \
    h0 = ov0 * fmaf(2.0f, __builtin_amdgcn_rcpf(1.0f + ec0), -1.0f);          \
    h1 = ov1 * fmaf(2.0f, __builtin_amdgcn_rcpf(1.0f + ec1), -1.0f);          \
    h2 = ov2 * fmaf(2.0f, __builtin_amdgcn_rcpf(1.0f + ec2), -1.0f);          \
} while (0)

    // prologue: two 8-step blocks in flight, wait until first is resident
    STAGE_BLK(0, 0);
    STAGE_BLK(1, 2048);
    WAITVM(2);
    __builtin_amdgcn_sched_barrier(0);

    float4 xa0, xa1, xa2, xa3, xb0, xb1, xb2, xb3;
    LOAD_XQ(xa0, xa1, xa2, xa3, 0, 0);

    for (int blk = 0; blk < 64; ++blk) {
        const int bufsel = (blk & 1) ? 2048 : 0;
#pragma unroll
        for (int s = 0; s < 8; ++s) {
            if ((s & 1) == 0) {
                if (s < 7) LOAD_XQ(xb0, xb1, xb2, xb3, bufsel, s + 1);
                STEP(xa0, xa1, xa2, xa3);
            } else {
                if (s < 7) LOAD_XQ(xa0, xa1, xa2, xa3, bufsel, s + 1);
                STEP(xb0, xb1, xb2, xb3);
            }
        }
        // buf[bufsel] fully consumed; refill with block blk+2
        __builtin_amdgcn_sched_barrier(0);
        if (blk + 2 < 64) {
            STAGE_BLK(blk + 2, bufsel);
            WAITVM(2);   // waits for block blk+1 (issued a full block of compute ago)
        } else {
            WAITVM(0);
        }
        __builtin_amdgcn_sched_barrier(0);
        if (blk < 63) {
            LOAD_XQ(xa0, xa1, xa2, xa3, bufsel ^ 2048, 0);
        }
    }

    if (lr == 0) {
        float acc = bdv;
        acc = fmaf(h0, wd0, acc);
        acc = fmaf(h1, wd1, acc);
        acc = fmaf(h2, wd2, acc);
        const float e = __builtin_amdgcn_exp2f(-LOG2E * acc);
        out[b] = __builtin_amdgcn_rcpf(1.0f + e);
    }
#undef STAGE_BLK
#undef LOAD_XQ
#undef STEP
}

extern "C" void kernel_launch(void* const* d_in, const int* in_sizes, int n_in,
                              void* d_out, int out_size, void* d_ws, size_t ws_size,
                              hipStream_t stream) {
    const float* X  = (const float*)d_in[0];
    const float* W  = (const float*)d_in[1];
    const float* U  = (const float*)d_in[2];
    const float* bg = (const float*)d_in[3];
    const float* Wd = (const float*)d_in[4];
    const float* bd = (const float*)d_in[5];
    float* out = (float*)d_out;

    dim3 grid(8192 / 16);   // 512 blocks x 256 threads = 2048 waves (2/SIMD)
    dim3 block(256);
    hipLaunchKernelGGL(lstm_or_staged_kernel, grid, block, 0, stream,
                       X, W, U, bg, Wd, bd, out);
}

// Round 13
// 142.872 us; speedup vs baseline: 1.4466x; 1.0567x over previous
//
#include <hip/hip_runtime.h>

#define LOG2E 1.44269504088896340736f

// ds_swizzle BitMode: src_lane = ((lane & and) | or) ^ xor; imm=(xor<<10)|(or<<5)|and
// Masks 0x01C/0x03C/0x05C proven in R2/R9/R10/R12 (keep bits[4:2], select unit).
#define SWZ(v, imm) __int_as_float(__builtin_amdgcn_ds_swizzle(__float_as_int(v), (imm)))

#define WAITVM(n) asm volatile("s_waitcnt vmcnt(" #n ")" ::: "memory")

// Zero-LDS datapath. Unit-owner layout (R10-proven numerics): lane k=tid&3
// owns unit min(k,2), computes all 4 gate columns locally; per-step cross-lane
// = 3 ds_swizzle h-broadcasts ONLY (DS-pipe demand ~70 cy/CU/step vs R12's
// ~940 — R12 was DS-pipe-bound). X is streamed through REGISTERS: double-
// buffered 4-step blocks (2 x 16 float4), global_load_dwordx4 issued one full
// compute-block (~1200 cy) ahead; FIFO vmcnt(16) waits target loads issued a
// block ago -> HBM latency structurally hidden, no LDS staging at all.
// 8 lanes/row = 2 redundant copies of the 4-lane group (swizzle and-mask 0x1C
// preserves the copy bit) -> 8 rows/wave, 1024 waves = 1/SIMD on every SIMD.
__global__ __launch_bounds__(256, 1)
void lstm_regpipe_kernel(const float* __restrict__ X,    // [8192,512,16]
                         const float* __restrict__ Wg,   // [16,12]
                         const float* __restrict__ Ug,   // [3,12]
                         const float* __restrict__ bg,   // [12]
                         const float* __restrict__ Wd,   // [3]
                         const float* __restrict__ bd,   // [1]
                         float* __restrict__ out)        // [8192]
{
    constexpr int T = 512;
    const int tid = threadIdx.x;      // 0..255
    const int k   = tid & 3;          // unit (3 dups 2)
    const int kk  = (k == 3) ? 2 : k;
    const int b   = blockIdx.x * 32 + (tid >> 3);   // 32 rows/block, 8 lanes/row

    const int ci = kk, cf = 3 + kk, cg = 6 + kk, co = 9 + kk;

    float wi[16], wf[16], wgt[16], wo[16];
#pragma unroll
    for (int f = 0; f < 16; ++f) {
        const float* row = Wg + (size_t)f * 12;
        wi[f] = row[ci]; wf[f] = row[cf]; wgt[f] = row[cg]; wo[f] = row[co];
    }
    const float ui0 = Ug[ci], ui1 = Ug[12+ci], ui2 = Ug[24+ci];
    const float uf0 = Ug[cf], uf1 = Ug[12+cf], uf2 = Ug[24+cf];
    const float ug0 = Ug[cg], ug1 = Ug[12+cg], ug2 = Ug[24+cg];
    const float uo0 = Ug[co], uo1 = Ug[12+co], uo2 = Ug[24+co];
    const float bias_i = bg[ci], bias_f = bg[cf], bias_g = bg[cg], bias_o = bg[co];
    const float wd0 = Wd[0], wd1 = Wd[1], wd2 = Wd[2], bdv = bd[0];

    float c = 0.f, h0 = 0.f, h1 = 0.f, h2 = 0.f;

    const float4* Xr = reinterpret_cast<const float4*>(X) + (size_t)b * (T * 4);

// 4 FMAs of one float4 against weight slice W[o..o+3]
#define G4(zz, W, V, o) do {                                                  \
    zz = fmaf((V).x, W[(o)+0], zz); zz = fmaf((V).y, W[(o)+1], zz);           \
    zz = fmaf((V).z, W[(o)+2], zz); zz = fmaf((V).w, W[(o)+3], zz);           \
} while (0)

#define STEP(X0, X1, X2, X3) do {                                             \
    float zi = bias_i, zf = bias_f, zg = bias_g, zo = bias_o;                 \
    G4(zi, wi,  X0, 0);  G4(zi, wi,  X1, 4);                                  \
    G4(zi, wi,  X2, 8);  G4(zi, wi,  X3, 12);                                 \
    G4(zf, wf,  X0, 0);  G4(zf, wf,  X1, 4);                                  \
    G4(zf, wf,  X2, 8);  G4(zf, wf,  X3, 12);                                 \
    G4(zg, wgt, X0, 0);  G4(zg, wgt, X1, 4);                                  \
    G4(zg, wgt, X2, 8);  G4(zg, wgt, X3, 12);                                 \
    G4(zo, wo,  X0, 0);  G4(zo, wo,  X1, 4);                                  \
    G4(zo, wo,  X2, 8);  G4(zo, wo,  X3, 12);                                 \
    zi = fmaf(h0, ui0, zi); zi = fmaf(h1, ui1, zi); zi = fmaf(h2, ui2, zi);   \
    zf = fmaf(h0, uf0, zf); zf = fmaf(h1, uf1, zf); zf = fmaf(h2, uf2, zf);   \
    zg = fmaf(h0, ug0, zg); zg = fmaf(h1, ug1, zg); zg = fmaf(h2, ug2, zg);   \
    zo = fmaf(h0, uo0, zo); zo = fmaf(h1, uo1, zo); zo = fmaf(h2, uo2, zo);   \
    const float ei = __builtin_amdgcn_exp2f(zi * (-LOG2E));                   \
    const float ef = __builtin_amdgcn_exp2f(zf * (-LOG2E));                   \
    const float eg = __builtin_amdgcn_exp2f(zg * (-2.0f * LOG2E));            \
    const float eo = __builtin_amdgcn_exp2f(zo * (-LOG2E));                   \
    const float ai = __builtin_amdgcn_rcpf(1.0f + ei);                        \
    const float af = __builtin_amdgcn_rcpf(1.0f + ef);                        \
    const float ag = fmaf(2.0f, __builtin_amdgcn_rcpf(1.0f + eg), -1.0f);     \
    const float ao = __builtin_amdgcn_rcpf(1.0f + eo);                        \
    c = fmaf(af, c, ai * ag);                                                 \
    const float ec = __builtin_amdgcn_exp2f(c * (-2.0f * LOG2E));             \
    const float th = fmaf(2.0f, __builtin_amdgcn_rcpf(1.0f + ec), -1.0f);     \
    const float hk = ao * th;                                                 \
    h0 = SWZ(hk, 0x01C); h1 = SWZ(hk, 0x03C); h2 = SWZ(hk, 0x05C);            \
} while (0)

// load one 4-step block (16 x global_load_dwordx4) into a register buffer
#define LOADBLK(BUF, tbase) do {                                              \
    const int tb_ = ((tbase) <= T - 4) ? (tbase) : (T - 4);                   \
    _Pragma("unroll")                                                         \
    for (int s_ = 0; s_ < 4; ++s_)                                            \
        _Pragma("unroll")                                                     \
        for (int p_ = 0; p_ < 4; ++p_)                                        \
            BUF[s_][p_] = Xr[(size_t)(tb_ + s_) * 4 + p_];                    \
} while (0)

    float4 xa[4][4], xb[4][4];

    // prologue: two blocks in flight; wait until first is resident
    LOADBLK(xa, 0);
    LOADBLK(xb, 4);
    WAITVM(16);

    for (int blk = 0; blk < 64; ++blk) {
        const int t0 = blk * 8;
        // compute steps t0..t0+3 from xa
        STEP(xa[0][0], xa[0][1], xa[0][2], xa[0][3]);
        STEP(xa[1][0], xa[1][1], xa[1][2], xa[1][3]);
        STEP(xa[2][0], xa[2][1], xa[2][2], xa[2][3]);
        STEP(xa[3][0], xa[3][1], xa[3][2], xa[3][3]);
        // refill xa with steps t0+8.. (clamped; last refills unused)
        LOADBLK(xa, t0 + 8);
        WAITVM(16);   // xb's loads (issued a full block of compute ago) done
        // compute steps t0+4..t0+7 from xb
        STEP(xb[0][0], xb[0][1], xb[0][2], xb[0][3]);
        STEP(xb[1][0], xb[1][1], xb[1][2], xb[1][3]);
        STEP(xb[2][0], xb[2][1], xb[2][2], xb[2][3]);
        STEP(xb[3][0], xb[3][1], xb[3][2], xb[3][3]);
        LOADBLK(xb, t0 + 12);
        WAITVM(16);   // xa's refill done
    }

    if ((tid & 7) == 0) {   // copy 0, unit 0 of each row
        float acc = bdv;
        acc = fmaf(h0, wd0, acc);
        acc = fmaf(h1, wd1, acc);
        acc = fmaf(h2, wd2, acc);
        const float e = __builtin_amdgcn_exp2f(-LOG2E * acc);
        out[b] = __builtin_amdgcn_rcpf(1.0f + e);
    }
#undef G4
#undef STEP
#undef LOADBLK
}

extern "C" void kernel_launch(void* const* d_in, const int* in_sizes, int n_in,
                              void* d_out, int out_size, void* d_ws, size_t ws_size,
                              hipStream_t stream) {
    const float* X  = (const float*)d_in[0];
    const float* W  = (const float*)d_in[1];
    const float* U  = (const float*)d_in[2];
    const float* bg = (const float*)d_in[3];
    const float* Wd = (const float*)d_in[4];
    const float* bd = (const float*)d_in[5];
    float* out = (float*)d_out;

    dim3 grid(8192 / 32);   // 256 blocks x 256 threads = 1024 waves (1/SIMD)
    dim3 block(256);
    hipLaunchKernelGGL(lstm_regpipe_kernel, grid, block, 0, stream,
                       X, W, U, bg, Wd, bd, out);
}